// Round 1
// baseline (4714.418 us; speedup 1.0000x reference)
//
#include <hip/hip_runtime.h>
#include <cstdint>

#define N_NODES 100000
#define N_EDGES 1600000
#define ETOT    1700000   // edges + self loops
#define FIN     512
#define HD1     64        // 8 heads * 8 dims
#define C2      40
#define NEG_SLOPE 0.2f

__device__ __forceinline__ float lrelu(float v) { return v > 0.f ? v : NEG_SLOPE * v; }

// ---------------- GEMM1: h1 = x @ W1  (100000x512 @ 512x64) ----------------
__global__ __launch_bounds__(256) void k_gemm1(const float* __restrict__ x,
                                               const float* __restrict__ W1,
                                               float* __restrict__ h1) {
    __shared__ float xs[64][36];   // [row][kk], pad 36 (144B row stride, 16B aligned)
    __shared__ float wsm[32][64];  // [kk][col]
    const int t    = threadIdx.x;
    const int cg   = t & 15;       // 4-col group
    const int rgp  = t >> 4;       // 4-row group, 0..15
    const int row0 = blockIdx.x * 64;

    float acc[4][4];
#pragma unroll
    for (int i = 0; i < 4; i++)
#pragma unroll
        for (int j = 0; j < 4; j++) acc[i][j] = 0.f;

    for (int kb = 0; kb < FIN; kb += 32) {
#pragma unroll
        for (int j = 0; j < 8; j++) {
            int i = t + j * 256;
            int r = i >> 5, kk = i & 31;
            int row = row0 + r;
            xs[r][kk] = (row < N_NODES) ? x[row * FIN + kb + kk] : 0.f;
        }
#pragma unroll
        for (int j = 0; j < 8; j++) {
            int i = t + j * 256;
            int kk = i >> 6, c = i & 63;
            wsm[kk][c] = W1[(kb + kk) * HD1 + c];
        }
        __syncthreads();
#pragma unroll
        for (int kk = 0; kk < 32; kk++) {
            float4 wv = *(const float4*)&wsm[kk][cg * 4];
#pragma unroll
            for (int r = 0; r < 4; r++) {
                float xv = xs[rgp * 4 + r][kk];
                acc[r][0] += xv * wv.x;
                acc[r][1] += xv * wv.y;
                acc[r][2] += xv * wv.z;
                acc[r][3] += xv * wv.w;
            }
        }
        __syncthreads();
    }
#pragma unroll
    for (int r = 0; r < 4; r++) {
        int row = row0 + rgp * 4 + r;
        if (row < N_NODES) {
            float4 v = make_float4(acc[r][0], acc[r][1], acc[r][2], acc[r][3]);
            *(float4*)&h1[row * HD1 + cg * 4] = v;
        }
    }
}

// ---------------- per-node attention logits, layer 1 ----------------
// thread per (n, h): as1[n*8+h] = sum_d h1[n,h,d]*att_src1[h,d]
__global__ void k_att1(const float* __restrict__ h1,
                       const float* __restrict__ a_s, const float* __restrict__ a_d,
                       float* __restrict__ as1, float* __restrict__ ad1) {
    int t = blockIdx.x * 256 + threadIdx.x;
    if (t >= N_NODES * 8) return;
    int h = t & 7;
    float4 v0 = *(const float4*)&h1[t * 8];
    float4 v1 = *(const float4*)&h1[t * 8 + 4];
    float4 s0 = *(const float4*)&a_s[h * 8], s1v = *(const float4*)&a_s[h * 8 + 4];
    float4 d0 = *(const float4*)&a_d[h * 8], d1v = *(const float4*)&a_d[h * 8 + 4];
    as1[t] = v0.x * s0.x + v0.y * s0.y + v0.z * s0.z + v0.w * s0.w +
             v1.x * s1v.x + v1.y * s1v.y + v1.z * s1v.z + v1.w * s1v.w;
    ad1[t] = v0.x * d0.x + v0.y * d0.y + v0.z * d0.z + v0.w * d0.w +
             v1.x * d1v.x + v1.y * d1v.y + v1.z * d1v.z + v1.w * d1v.w;
}

// ---------------- layer-1 softmax denominators ----------------
__global__ void k_s1(const int* __restrict__ ei,
                     const float* __restrict__ as1, const float* __restrict__ ad1,
                     float* __restrict__ s1) {
    int e = blockIdx.x * 256 + threadIdx.x;
    if (e >= ETOT) return;
    int src, dst;
    if (e < N_EDGES) { src = ei[e]; dst = ei[N_EDGES + e]; }
    else             { src = dst = e - N_EDGES; }
#pragma unroll
    for (int h = 0; h < 8; h++) {
        float lg = lrelu(as1[src * 8 + h] + ad1[dst * 8 + h]);
        atomicAdd(&s1[dst * 8 + h], __expf(lg));
    }
}

// ---------------- layer-1 weighted aggregation ----------------
// thread per (edge, head)
__global__ void k_agg1(const int* __restrict__ ei, const float* __restrict__ h1,
                       const float* __restrict__ as1, const float* __restrict__ ad1,
                       const float* __restrict__ s1, float* __restrict__ ob) {
    int t = blockIdx.x * 256 + threadIdx.x;
    if (t >= ETOT * 8) return;
    int e = t >> 3, h = t & 7;
    int src, dst;
    if (e < N_EDGES) { src = ei[e]; dst = ei[N_EDGES + e]; }
    else             { src = dst = e - N_EDGES; }
    float lg    = lrelu(as1[src * 8 + h] + ad1[dst * 8 + h]);
    float alpha = __expf(lg) / (s1[dst * 8 + h] + 1e-16f);
    const float4* hp = (const float4*)&h1[src * HD1 + h * 8];
    float4 v0 = hp[0], v1 = hp[1];
    float* o = &ob[dst * HD1 + h * 8];
    atomicAdd(o + 0, alpha * v0.x);
    atomicAdd(o + 1, alpha * v0.y);
    atomicAdd(o + 2, alpha * v0.z);
    atomicAdd(o + 3, alpha * v0.w);
    atomicAdd(o + 4, alpha * v1.x);
    atomicAdd(o + 5, alpha * v1.y);
    atomicAdd(o + 6, alpha * v1.z);
    atomicAdd(o + 7, alpha * v1.w);
}

// ---------------- bias + ELU (in place) ----------------
__global__ void k_elu1(float* __restrict__ ob, const float* __restrict__ b1) {
    int t = blockIdx.x * 256 + threadIdx.x;
    if (t >= N_NODES * HD1) return;
    float v = ob[t] + b1[t & 63];
    ob[t] = v > 0.f ? v : expm1f(v);
}

// ---------------- GEMM2 + layer-2 attention logits ----------------
// one wave per row: h2[n,:40] = h[n,:64] @ W2; as2[n], ad2[n] dot-reductions
__global__ __launch_bounds__(256) void k_gemm2(const float* __restrict__ h,
                                               const float* __restrict__ W2,
                                               const float* __restrict__ atts,
                                               const float* __restrict__ attd,
                                               float* __restrict__ h2,
                                               float* __restrict__ as2, float* __restrict__ ad2) {
    __shared__ float w2s[64 * C2];
    int t = threadIdx.x, lane = t & 63, wv = t >> 6;
    for (int i = t; i < 64 * C2; i += 256) w2s[i] = W2[i];
    __syncthreads();
    int row = blockIdx.x * 4 + wv;
    if (row >= N_NODES) return;
    float hv = h[row * HD1 + lane];
    int c = lane < C2 ? lane : 0;
    float acc = 0.f;
#pragma unroll
    for (int k = 0; k < 64; k++) {
        float b = __shfl(hv, k, 64);
        acc += b * w2s[k * C2 + c];
    }
    float sa = (lane < C2) ? acc * atts[c] : 0.f;
    float da = (lane < C2) ? acc * attd[c] : 0.f;
#pragma unroll
    for (int o = 32; o >= 1; o >>= 1) {
        sa += __shfl_xor(sa, o, 64);
        da += __shfl_xor(da, o, 64);
    }
    if (lane < C2) h2[row * C2 + lane] = acc;
    if (lane == 0) { as2[row] = sa; ad2[row] = da; }
}

// ---------------- layer-2 softmax denominators ----------------
__global__ void k_s2(const int* __restrict__ ei,
                     const float* __restrict__ as2, const float* __restrict__ ad2,
                     float* __restrict__ s2) {
    int e = blockIdx.x * 256 + threadIdx.x;
    if (e >= ETOT) return;
    int src, dst;
    if (e < N_EDGES) { src = ei[e]; dst = ei[N_EDGES + e]; }
    else             { src = dst = e - N_EDGES; }
    atomicAdd(&s2[dst], __expf(lrelu(as2[src] + ad2[dst])));
}

// ---------------- layer-2 weighted aggregation into d_out ----------------
// thread per (edge, channel)
__global__ void k_agg2(const int* __restrict__ ei, const float* __restrict__ h2,
                       const float* __restrict__ as2, const float* __restrict__ ad2,
                       const float* __restrict__ s2, float* __restrict__ out) {
    int t = blockIdx.x * 256 + threadIdx.x;
    if (t >= ETOT * C2) return;
    int e = t / C2;
    int c = t - e * C2;
    int src, dst;
    if (e < N_EDGES) { src = ei[e]; dst = ei[N_EDGES + e]; }
    else             { src = dst = e - N_EDGES; }
    float alpha = __expf(lrelu(as2[src] + ad2[dst])) / (s2[dst] + 1e-16f);
    atomicAdd(&out[dst * C2 + c], alpha * h2[src * C2 + c]);
}

// ---------------- bias + log_softmax (in place on d_out) ----------------
__global__ __launch_bounds__(256) void k_lsm(float* __restrict__ out, const float* __restrict__ b2) {
    int row = blockIdx.x * 4 + (threadIdx.x >> 6);
    int lane = threadIdx.x & 63;
    if (row >= N_NODES) return;
    float v = (lane < C2) ? out[row * C2 + lane] + b2[lane] : -1e30f;
    float m = v;
#pragma unroll
    for (int o = 32; o >= 1; o >>= 1) m = fmaxf(m, __shfl_xor(m, o, 64));
    float ex = (lane < C2) ? __expf(v - m) : 0.f;
    float s = ex;
#pragma unroll
    for (int o = 32; o >= 1; o >>= 1) s += __shfl_xor(s, o, 64);
    if (lane < C2) out[row * C2 + lane] = v - m - logf(s);
}

extern "C" void kernel_launch(void* const* d_in, const int* in_sizes, int n_in,
                              void* d_out, int out_size, void* d_ws, size_t ws_size,
                              hipStream_t stream) {
    const float* x    = (const float*)d_in[0];
    const int*   ei   = (const int*)d_in[1];
    const float* W1   = (const float*)d_in[2];
    const float* at_s1 = (const float*)d_in[3];
    const float* at_d1 = (const float*)d_in[4];
    const float* b1   = (const float*)d_in[5];
    const float* W2   = (const float*)d_in[6];
    const float* at_s2 = (const float*)d_in[7];
    const float* at_d2 = (const float*)d_in[8];
    const float* b2   = (const float*)d_in[9];
    float* out = (float*)d_out;
    float* ws  = (float*)d_ws;

    // workspace layout (element offsets)
    float* h1   = ws;               // N*64  (reused as h2: N*40)
    float* hbuf = ws + 6400000;     // N*64  (out1 accum, then ELU'd h, in place)
    float* as1  = ws + 12800000;    // N*8
    float* ad1  = ws + 13600000;    // N*8
    float* s1   = ws + 14400000;    // N*8
    float* as2  = ws + 15200000;    // N
    float* ad2  = ws + 15300000;    // N
    float* s2   = ws + 15400000;    // N
    float* h2   = h1;               // reuse after layer-1 aggregation

    // zero accumulators (ws/out are poisoned 0xAA before every launch)
    hipMemsetAsync(hbuf, 0, (size_t)N_NODES * HD1 * sizeof(float), stream);
    hipMemsetAsync(s1,   0, (size_t)N_NODES * 8 * sizeof(float), stream);
    hipMemsetAsync(s2,   0, (size_t)N_NODES * sizeof(float), stream);
    hipMemsetAsync(out,  0, (size_t)N_NODES * C2 * sizeof(float), stream);

    k_gemm1<<<(N_NODES + 63) / 64, 256, 0, stream>>>(x, W1, h1);
    k_att1<<<(N_NODES * 8 + 255) / 256, 256, 0, stream>>>(h1, at_s1, at_d1, as1, ad1);
    k_s1<<<(ETOT + 255) / 256, 256, 0, stream>>>(ei, as1, ad1, s1);
    k_agg1<<<(ETOT * 8 + 255) / 256, 256, 0, stream>>>(ei, h1, as1, ad1, s1, hbuf);
    k_elu1<<<(N_NODES * HD1 + 255) / 256, 256, 0, stream>>>(hbuf, b1);
    k_gemm2<<<(N_NODES + 3) / 4, 256, 0, stream>>>(hbuf, W2, at_s2, at_d2, h2, as2, ad2);
    k_s2<<<(ETOT + 255) / 256, 256, 0, stream>>>(ei, as2, ad2, s2);
    k_agg2<<<((long long)ETOT * C2 + 255) / 256, 256, 0, stream>>>(ei, h2, as2, ad2, s2, out);
    k_lsm<<<(N_NODES + 3) / 4, 256, 0, stream>>>(out, b2);
}

// Round 2
// 1218.905 us; speedup vs baseline: 3.8677x; 3.8677x over previous
//
#include <hip/hip_runtime.h>
#include <cstdint>

#define N_NODES 100000
#define N_EDGES 1600000
#define ETOT    1700000   // edges + self loops
#define FIN     512
#define HD1     64        // 8 heads * 8 dims
#define C2      40
#define NEG_SLOPE 0.2f

__device__ __forceinline__ float lrelu(float v) { return v > 0.f ? v : NEG_SLOPE * v; }

// ---------------- GEMM1: h1 = x @ W1  (100000x512 @ 512x64) ----------------
__global__ __launch_bounds__(256) void k_gemm1(const float* __restrict__ x,
                                               const float* __restrict__ W1,
                                               float* __restrict__ h1) {
    __shared__ float xs[64][36];
    __shared__ float wsm[32][64];
    const int t    = threadIdx.x;
    const int cg   = t & 15;
    const int rgp  = t >> 4;
    const int row0 = blockIdx.x * 64;

    float acc[4][4];
#pragma unroll
    for (int i = 0; i < 4; i++)
#pragma unroll
        for (int j = 0; j < 4; j++) acc[i][j] = 0.f;

    for (int kb = 0; kb < FIN; kb += 32) {
#pragma unroll
        for (int j = 0; j < 8; j++) {
            int i = t + j * 256;
            int r = i >> 5, kk = i & 31;
            int row = row0 + r;
            xs[r][kk] = (row < N_NODES) ? x[row * FIN + kb + kk] : 0.f;
        }
#pragma unroll
        for (int j = 0; j < 8; j++) {
            int i = t + j * 256;
            int kk = i >> 6, c = i & 63;
            wsm[kk][c] = W1[(kb + kk) * HD1 + c];
        }
        __syncthreads();
#pragma unroll
        for (int kk = 0; kk < 32; kk++) {
            float4 wv = *(const float4*)&wsm[kk][cg * 4];
#pragma unroll
            for (int r = 0; r < 4; r++) {
                float xv = xs[rgp * 4 + r][kk];
                acc[r][0] += xv * wv.x;
                acc[r][1] += xv * wv.y;
                acc[r][2] += xv * wv.z;
                acc[r][3] += xv * wv.w;
            }
        }
        __syncthreads();
    }
#pragma unroll
    for (int r = 0; r < 4; r++) {
        int row = row0 + rgp * 4 + r;
        if (row < N_NODES) {
            float4 v = make_float4(acc[r][0], acc[r][1], acc[r][2], acc[r][3]);
            *(float4*)&h1[row * HD1 + cg * 4] = v;
        }
    }
}

// ---------------- per-node attention logits, layer 1 ----------------
__global__ void k_att1(const float* __restrict__ h1,
                       const float* __restrict__ a_s, const float* __restrict__ a_d,
                       float* __restrict__ as1, float* __restrict__ ad1) {
    int t = blockIdx.x * 256 + threadIdx.x;
    if (t >= N_NODES * 8) return;
    int h = t & 7;
    float4 v0 = *(const float4*)&h1[t * 8];
    float4 v1 = *(const float4*)&h1[t * 8 + 4];
    float4 s0 = *(const float4*)&a_s[h * 8], s1v = *(const float4*)&a_s[h * 8 + 4];
    float4 d0 = *(const float4*)&a_d[h * 8], d1v = *(const float4*)&a_d[h * 8 + 4];
    as1[t] = v0.x * s0.x + v0.y * s0.y + v0.z * s0.z + v0.w * s0.w +
             v1.x * s1v.x + v1.y * s1v.y + v1.z * s1v.z + v1.w * s1v.w;
    ad1[t] = v0.x * d0.x + v0.y * d0.y + v0.z * d0.z + v0.w * d0.w +
             v1.x * d1v.x + v1.y * d1v.y + v1.z * d1v.z + v1.w * d1v.w;
}

// ---------------- CSR build: degree histogram ----------------
__global__ void k_deg(const int* __restrict__ ei, int* __restrict__ deg) {
    int e = blockIdx.x * 256 + threadIdx.x;
    if (e >= ETOT) return;
    int dst = (e < N_EDGES) ? ei[N_EDGES + e] : e - N_EDGES;
    atomicAdd(&deg[dst], 1);
}

// ---------------- CSR build: exclusive scan (single block) ----------------
__global__ __launch_bounds__(1024) void k_scan(const int* __restrict__ deg,
                                               int* __restrict__ row_ptr) {
    __shared__ int ps[1024];
    int t = threadIdx.x;
    const int CH = (N_NODES + 1023) / 1024;  // 98
    int b = t * CH;
    int s = 0;
    for (int i = 0; i < CH; i++) { int idx = b + i; if (idx < N_NODES) s += deg[idx]; }
    ps[t] = s;
    __syncthreads();
    for (int off = 1; off < 1024; off <<= 1) {
        int v = (t >= off) ? ps[t - off] : 0;
        __syncthreads();
        ps[t] += v;
        __syncthreads();
    }
    int run = ps[t] - s;  // exclusive prefix
    for (int i = 0; i < CH; i++) {
        int idx = b + i;
        if (idx < N_NODES) { row_ptr[idx] = run; run += deg[idx]; }
    }
    if (t == 1023) row_ptr[N_NODES] = ps[1023];
}

// ---------------- CSR build: scatter src by dst ----------------
__global__ void k_scatter(const int* __restrict__ ei, const int* __restrict__ row_ptr,
                          int* __restrict__ cnt, int* __restrict__ csr_src) {
    int e = blockIdx.x * 256 + threadIdx.x;
    if (e >= ETOT) return;
    int src, dst;
    if (e < N_EDGES) { src = ei[e]; dst = ei[N_EDGES + e]; }
    else             { src = dst = e - N_EDGES; }
    int pos = row_ptr[dst] + atomicAdd(&cnt[dst], 1);
    csr_src[pos] = src;
}

// ---------------- layer 1: gather-aggregate + ELU + GEMM2 + att2 logits ----------------
// one wave per dst node; lane = channel (0..63)
__global__ __launch_bounds__(256) void k_agg1f(
    const float* __restrict__ h1,
    const float* __restrict__ as1, const float* __restrict__ ad1,
    const int* __restrict__ row_ptr, const int* __restrict__ csr_src,
    const float* __restrict__ b1, const float* __restrict__ W2,
    const float* __restrict__ att_s2, const float* __restrict__ att_d2,
    float* __restrict__ h2, float* __restrict__ as2, float* __restrict__ ad2) {
    __shared__ float w2s[64 * C2];
    int t = threadIdx.x;
    for (int i = t; i < 64 * C2; i += 256) w2s[i] = W2[i];
    __syncthreads();
    int wv = t >> 6, lane = t & 63;
    int dst = blockIdx.x * 4 + wv;
    if (dst >= N_NODES) return;
    int h = lane >> 3;
    int s0 = row_ptr[dst], s1e = row_ptr[dst + 1];
    float ad = ad1[dst * 8 + h];
    float acc = 0.f, den = 0.f;
    for (int base = s0; base < s1e; base += 64) {
        int idx = base + lane;
        int msrc = (idx < s1e) ? csr_src[idx] : 0;
        int cnt = min(64, s1e - base);
        for (int j = 0; j < cnt; j++) {
            int s = __shfl(msrc, j, 64);
            float w = __expf(lrelu(as1[s * 8 + h] + ad));
            den += w;
            acc += w * h1[s * 64 + lane];
        }
    }
    float hv = acc / (den + 1e-16f) + b1[lane];
    hv = hv > 0.f ? hv : expm1f(hv);
    // fused GEMM2 (64->40) + layer-2 attention logits
    int c = (lane < C2) ? lane : 0;
    float a2 = 0.f;
#pragma unroll
    for (int k = 0; k < 64; k++) a2 += __shfl(hv, k, 64) * w2s[k * C2 + c];
    float sa = (lane < C2) ? a2 * att_s2[c] : 0.f;
    float da = (lane < C2) ? a2 * att_d2[c] : 0.f;
#pragma unroll
    for (int o = 32; o >= 1; o >>= 1) {
        sa += __shfl_xor(sa, o, 64);
        da += __shfl_xor(da, o, 64);
    }
    if (lane < C2) h2[dst * C2 + lane] = a2;
    if (lane == 0) { as2[dst] = sa; ad2[dst] = da; }
}

// ---------------- layer 2: gather-aggregate + bias + log_softmax ----------------
__global__ __launch_bounds__(256) void k_agg2f(
    const float* __restrict__ h2,
    const float* __restrict__ as2, const float* __restrict__ ad2,
    const int* __restrict__ row_ptr, const int* __restrict__ csr_src,
    const float* __restrict__ b2, float* __restrict__ out) {
    int t = threadIdx.x, wv = t >> 6, lane = t & 63;
    int dst = blockIdx.x * 4 + wv;
    if (dst >= N_NODES) return;
    int s0 = row_ptr[dst], s1e = row_ptr[dst + 1];
    float ad = ad2[dst];
    bool act = lane < C2;
    float acc = 0.f, den = 0.f;
    for (int base = s0; base < s1e; base += 64) {
        int idx = base + lane;
        int msrc = (idx < s1e) ? csr_src[idx] : 0;
        int cnt = min(64, s1e - base);
        for (int j = 0; j < cnt; j++) {
            int s = __shfl(msrc, j, 64);
            float w = __expf(lrelu(as2[s] + ad));
            den += w;
            if (act) acc += w * h2[s * C2 + lane];
        }
    }
    float v = act ? acc / (den + 1e-16f) + b2[lane] : -1e30f;
    float m = v;
#pragma unroll
    for (int o = 32; o >= 1; o >>= 1) m = fmaxf(m, __shfl_xor(m, o, 64));
    float ex = act ? __expf(v - m) : 0.f;
    float ssum = ex;
#pragma unroll
    for (int o = 32; o >= 1; o >>= 1) ssum += __shfl_xor(ssum, o, 64);
    if (act) out[dst * C2 + lane] = v - m - logf(ssum);
}

extern "C" void kernel_launch(void* const* d_in, const int* in_sizes, int n_in,
                              void* d_out, int out_size, void* d_ws, size_t ws_size,
                              hipStream_t stream) {
    const float* x     = (const float*)d_in[0];
    const int*   ei    = (const int*)d_in[1];
    const float* W1    = (const float*)d_in[2];
    const float* at_s1 = (const float*)d_in[3];
    const float* at_d1 = (const float*)d_in[4];
    const float* b1    = (const float*)d_in[5];
    const float* W2    = (const float*)d_in[6];
    const float* at_s2 = (const float*)d_in[7];
    const float* at_d2 = (const float*)d_in[8];
    const float* b2    = (const float*)d_in[9];
    float* out = (float*)d_out;
    float* ws  = (float*)d_ws;

    // workspace layout (element offsets, fp32 elements)
    float* h1   = ws;                    // N*64
    float* as1  = ws + 6400000;          // N*8
    float* ad1  = ws + 7200000;          // N*8
    float* h2   = ws + 8000000;          // N*40
    float* as2  = ws + 12000000;         // N
    float* ad2  = ws + 12100000;         // N
    int* row_ptr = (int*)(ws + 12200000);  // N+1
    int* deg     = (int*)(ws + 12350000);  // N
    int* cnt     = (int*)(ws + 12500000);  // N
    int* csr_src = (int*)(ws + 12650000);  // ETOT

    hipMemsetAsync(deg, 0, (size_t)N_NODES * sizeof(int), stream);
    hipMemsetAsync(cnt, 0, (size_t)N_NODES * sizeof(int), stream);

    k_gemm1<<<(N_NODES + 63) / 64, 256, 0, stream>>>(x, W1, h1);
    k_att1<<<(N_NODES * 8 + 255) / 256, 256, 0, stream>>>(h1, at_s1, at_d1, as1, ad1);
    k_deg<<<(ETOT + 255) / 256, 256, 0, stream>>>(ei, deg);
    k_scan<<<1, 1024, 0, stream>>>(deg, row_ptr);
    k_scatter<<<(ETOT + 255) / 256, 256, 0, stream>>>(ei, row_ptr, cnt, csr_src);
    k_agg1f<<<(N_NODES + 3) / 4, 256, 0, stream>>>(h1, as1, ad1, row_ptr, csr_src,
                                                   b1, W2, at_s2, at_d2, h2, as2, ad2);
    k_agg2f<<<(N_NODES + 3) / 4, 256, 0, stream>>>(h2, as2, ad2, row_ptr, csr_src, b2, out);
}

// Round 3
// 889.842 us; speedup vs baseline: 5.2980x; 1.3698x over previous
//
#include <hip/hip_runtime.h>
#include <cstdint>

#define N_NODES 100000
#define N_EDGES 1600000
#define ETOT    1700000   // edges + self loops
#define FIN     512
#define HD1     64        // 8 heads * 8 dims
#define NB      80        // 64 h1 cols + 8 as1 + 8 ad1
#define C2      40
#define NEG_SLOPE 0.2f

typedef __attribute__((ext_vector_type(8))) short bf16x8;
typedef __attribute__((ext_vector_type(4))) float f32x4;

__device__ __forceinline__ float lrelu(float v) { return v > 0.f ? v : NEG_SLOPE * v; }

__device__ __forceinline__ unsigned short f2bf(float f) {
    uint32_t u = __float_as_uint(f);
    u += 0x7FFF + ((u >> 16) & 1);   // round-to-nearest-even
    return (unsigned short)(u >> 16);
}
__device__ __forceinline__ float bf2f(unsigned short u) {
    return __uint_as_float(((uint32_t)u) << 16);
}

// ---------------- prep: W1t[80][512] bf16 = [W1^T ; (W1*att_src1)^T ; (W1*att_dst1)^T] ----
__global__ void k_prep(const float* __restrict__ W1, const float* __restrict__ a_s,
                       const float* __restrict__ a_d, unsigned short* __restrict__ W1t) {
    int t = blockIdx.x * 256 + threadIdx.x;
    if (t >= NB * FIN) return;
    int n = t >> 9, k = t & 511;
    float v;
    if (n < 64) {
        v = W1[k * HD1 + n];
    } else if (n < 72) {
        int h = n - 64; v = 0.f;
#pragma unroll
        for (int d = 0; d < 8; d++) v += W1[k * HD1 + h * 8 + d] * a_s[h * 8 + d];
    } else {
        int h = n - 72; v = 0.f;
#pragma unroll
        for (int d = 0; d < 8; d++) v += W1[k * HD1 + h * 8 + d] * a_d[h * 8 + d];
    }
    W1t[n * FIN + k] = f2bf(v);
}

// ---------------- GEMM1 (MFMA bf16): [h1b | as1 | ad1] = x @ W1t^T ----------------
// block: 256 thr = 4 waves; tile M=128 (wave: 32 rows), N=80 (5 n-tiles of 16)
__global__ __launch_bounds__(256) void k_gemm1(const float* __restrict__ x,
                                               const unsigned short* __restrict__ W1t,
                                               unsigned short* __restrict__ h1b,
                                               float* __restrict__ as1,
                                               float* __restrict__ ad1) {
    __shared__ unsigned short As[128 * 72];   // chunk of x in bf16, row stride 72 (pad 8)
    const int t    = threadIdx.x;
    const int lane = t & 63, wv = t >> 6;
    const int quad = lane >> 4, l16 = lane & 15;
    const int row0 = blockIdx.x * 128;

    f32x4 acc[2][5];
#pragma unroll
    for (int mi = 0; mi < 2; mi++)
#pragma unroll
        for (int ni = 0; ni < 5; ni++) acc[mi][ni] = (f32x4){0.f, 0.f, 0.f, 0.f};

    float4 rx[8];
    // preload chunk 0
#pragma unroll
    for (int i = 0; i < 8; i++) {
        int ff = t + i * 256;
        int r = ff >> 4, c4 = ff & 15;
        int row = row0 + r;
        rx[i] = (row < N_NODES) ? *(const float4*)&x[(size_t)row * FIN + c4 * 4]
                                : make_float4(0.f, 0.f, 0.f, 0.f);
    }

    for (int c = 0; c < 8; c++) {
        // convert + store chunk c to LDS
#pragma unroll
        for (int i = 0; i < 8; i++) {
            int ff = t + i * 256;
            int r = ff >> 4, c4 = ff & 15;
            ushort4 s4;
            s4.x = f2bf(rx[i].x); s4.y = f2bf(rx[i].y);
            s4.z = f2bf(rx[i].z); s4.w = f2bf(rx[i].w);
            *(ushort4*)&As[r * 72 + c4 * 4] = s4;
        }
        __syncthreads();
        // prefetch chunk c+1 into registers (overlaps with MFMA below)
        if (c < 7) {
            int kb = (c + 1) * 64;
#pragma unroll
            for (int i = 0; i < 8; i++) {
                int ff = t + i * 256;
                int r = ff >> 4, c4 = ff & 15;
                int row = row0 + r;
                rx[i] = (row < N_NODES) ? *(const float4*)&x[(size_t)row * FIN + kb + c4 * 4]
                                        : make_float4(0.f, 0.f, 0.f, 0.f);
            }
        }
        int kb = c * 64;
#pragma unroll
        for (int ks = 0; ks < 2; ks++) {
            bf16x8 af[2], bf[5];
#pragma unroll
            for (int mi = 0; mi < 2; mi++) {
                int lr = wv * 32 + mi * 16 + l16;
                af[mi] = *(const bf16x8*)&As[lr * 72 + ks * 32 + quad * 8];
            }
#pragma unroll
            for (int ni = 0; ni < 5; ni++) {
                int n = ni * 16 + l16;
                bf[ni] = *(const bf16x8*)&W1t[n * FIN + kb + ks * 32 + quad * 8];
            }
#pragma unroll
            for (int mi = 0; mi < 2; mi++)
#pragma unroll
                for (int ni = 0; ni < 5; ni++)
                    acc[mi][ni] = __builtin_amdgcn_mfma_f32_16x16x32_bf16(
                        af[mi], bf[ni], acc[mi][ni], 0, 0, 0);
        }
        __syncthreads();
    }
    // epilogue: cols 0..63 -> h1b (bf16), 64..71 -> as1, 72..79 -> ad1
#pragma unroll
    for (int mi = 0; mi < 2; mi++)
#pragma unroll
        for (int ni = 0; ni < 5; ni++)
#pragma unroll
            for (int r = 0; r < 4; r++) {
                int row = row0 + wv * 32 + mi * 16 + quad * 4 + r;
                if (row >= N_NODES) continue;
                int col = ni * 16 + l16;
                float v = acc[mi][ni][r];
                if (col < 64)       h1b[(size_t)row * 64 + col] = f2bf(v);
                else if (col < 72)  as1[row * 8 + (col - 64)] = v;
                else                ad1[row * 8 + (col - 72)] = v;
            }
}

// ---------------- CSR build ----------------
__global__ void k_deg(const int* __restrict__ ei, int* __restrict__ deg) {
    int e = blockIdx.x * 256 + threadIdx.x;
    if (e >= ETOT) return;
    int dst = (e < N_EDGES) ? ei[N_EDGES + e] : e - N_EDGES;
    atomicAdd(&deg[dst], 1);
}

__global__ __launch_bounds__(1024) void k_scan(const int* __restrict__ deg,
                                               int* __restrict__ row_ptr) {
    __shared__ int ps[1024];
    int t = threadIdx.x;
    const int CH = (N_NODES + 1023) / 1024;  // 98
    int b = t * CH;
    int s = 0;
    for (int i = 0; i < CH; i++) { int idx = b + i; if (idx < N_NODES) s += deg[idx]; }
    ps[t] = s;
    __syncthreads();
    for (int off = 1; off < 1024; off <<= 1) {
        int v = (t >= off) ? ps[t - off] : 0;
        __syncthreads();
        ps[t] += v;
        __syncthreads();
    }
    int run = ps[t] - s;
    for (int i = 0; i < CH; i++) {
        int idx = b + i;
        if (idx < N_NODES) { row_ptr[idx] = run; run += deg[idx]; }
    }
    if (t == 1023) row_ptr[N_NODES] = ps[1023];
}

__global__ void k_scatter(const int* __restrict__ ei, const int* __restrict__ row_ptr,
                          int* __restrict__ cnt, int* __restrict__ csr_src) {
    int e = blockIdx.x * 256 + threadIdx.x;
    if (e >= ETOT) return;
    int src, dst;
    if (e < N_EDGES) { src = ei[e]; dst = ei[N_EDGES + e]; }
    else             { src = dst = e - N_EDGES; }
    int pos = row_ptr[dst] + atomicAdd(&cnt[dst], 1);
    csr_src[pos] = src;
}

// ---------------- layer 1: gather-aggregate + ELU + GEMM2 + att2 logits ----------------
// one wave per dst; lane = channel (h = lane>>3, d = lane&7)
__global__ __launch_bounds__(256) void k_agg1f(
    const unsigned short* __restrict__ h1b,
    const float* __restrict__ as1, const float* __restrict__ ad1,
    const int* __restrict__ row_ptr, const int* __restrict__ csr_src,
    const float* __restrict__ b1, const float* __restrict__ W2,
    const float* __restrict__ att_s2, const float* __restrict__ att_d2,
    unsigned short* __restrict__ h2b, float* __restrict__ as2, float* __restrict__ ad2) {
    __shared__ float w2s[64 * C2];
    int t = threadIdx.x;
    for (int i = t; i < 64 * C2; i += 256) w2s[i] = W2[i];
    __syncthreads();
    int wv = t >> 6, lane = t & 63;
    int dst = blockIdx.x * 4 + wv;
    if (dst >= N_NODES) return;
    int h  = lane >> 3;   // head for this channel
    int hh = lane & 7;    // head this lane precomputes weights for
    int s0 = row_ptr[dst], s1e = row_ptr[dst + 1];
    float adh = ad1[dst * 8 + hh];
    float acc = 0.f, den = 0.f;
    for (int base = s0; base < s1e; base += 8) {
        // phase 1: 64 lanes = 8 edges x 8 heads -> per-(edge,head) weight
        int eidx = base + (lane >> 3);
        bool vld = eidx < s1e;
        int sl = vld ? csr_src[eidx] : 0;
        float wl = vld ? __expf(lrelu(as1[sl * 8 + hh] + adh)) : 0.f;
        // phase 2: branchless broadcast loop, 8 independent gathers in flight
#pragma unroll
        for (int j = 0; j < 8; j++) {
            int s   = __shfl(sl, j * 8);
            float w = __shfl(wl, j * 8 + h);
            den += w;
            acc += w * bf2f(h1b[(size_t)s * 64 + lane]);
        }
    }
    float hv = acc / (den + 1e-16f) + b1[lane];
    hv = hv > 0.f ? hv : expm1f(hv);
    // fused GEMM2 (64->40) + layer-2 attention logits
    int c = (lane < C2) ? lane : 0;
    float a2 = 0.f;
#pragma unroll
    for (int k = 0; k < 64; k++) a2 += __shfl(hv, k, 64) * w2s[k * C2 + c];
    float sa = (lane < C2) ? a2 * att_s2[c] : 0.f;
    float da = (lane < C2) ? a2 * att_d2[c] : 0.f;
#pragma unroll
    for (int o = 32; o >= 1; o >>= 1) {
        sa += __shfl_xor(sa, o, 64);
        da += __shfl_xor(da, o, 64);
    }
    if (lane < C2) h2b[(size_t)dst * C2 + lane] = f2bf(a2);
    if (lane == 0) { as2[dst] = sa; ad2[dst] = da; }
}

// ---------------- layer 2: gather-aggregate + bias + log_softmax ----------------
__global__ __launch_bounds__(256) void k_agg2f(
    const unsigned short* __restrict__ h2b,
    const float* __restrict__ as2, const float* __restrict__ ad2,
    const int* __restrict__ row_ptr, const int* __restrict__ csr_src,
    const float* __restrict__ b2, float* __restrict__ out) {
    int t = threadIdx.x, wv = t >> 6, lane = t & 63;
    int dst = blockIdx.x * 4 + wv;
    if (dst >= N_NODES) return;
    int s0 = row_ptr[dst], s1e = row_ptr[dst + 1];
    float ad = ad2[dst];
    bool act = lane < C2;
    int cl = act ? lane : 0;
    float acc = 0.f, den = 0.f;
    for (int base = s0; base < s1e; base += 64) {
        int idx = base + lane;
        bool vld = idx < s1e;
        int sl = vld ? csr_src[idx] : 0;
        float wl = vld ? __expf(lrelu(as2[sl] + ad)) : 0.f;
        // denominator = wave-sum of precomputed weights
        float d = wl;
#pragma unroll
        for (int o = 32; o >= 1; o >>= 1) d += __shfl_xor(d, o, 64);
        den += d;
        int cnt  = min(64, s1e - base);
        int cnt4 = (cnt + 3) & ~3;
        for (int j = 0; j < cnt4; j += 4) {
#pragma unroll
            for (int jj = 0; jj < 4; jj++) {
                int s   = __shfl(sl, j + jj);
                float w = __shfl(wl, j + jj);
                float hvv = bf2f(h2b[(size_t)s * C2 + cl]);
                if (act) acc += w * hvv;
            }
        }
    }
    float v = act ? acc / (den + 1e-16f) + b2[cl] : -1e30f;
    float m = v;
#pragma unroll
    for (int o = 32; o >= 1; o >>= 1) m = fmaxf(m, __shfl_xor(m, o, 64));
    float ex = act ? __expf(v - m) : 0.f;
    float ssum = ex;
#pragma unroll
    for (int o = 32; o >= 1; o >>= 1) ssum += __shfl_xor(ssum, o, 64);
    if (act) out[(size_t)dst * C2 + lane] = v - m - logf(ssum);
}

extern "C" void kernel_launch(void* const* d_in, const int* in_sizes, int n_in,
                              void* d_out, int out_size, void* d_ws, size_t ws_size,
                              hipStream_t stream) {
    const float* x     = (const float*)d_in[0];
    const int*   ei    = (const int*)d_in[1];
    const float* W1    = (const float*)d_in[2];
    const float* at_s1 = (const float*)d_in[3];
    const float* at_d1 = (const float*)d_in[4];
    const float* b1    = (const float*)d_in[5];
    const float* W2    = (const float*)d_in[6];
    const float* at_s2 = (const float*)d_in[7];
    const float* at_d2 = (const float*)d_in[8];
    const float* b2    = (const float*)d_in[9];
    float* out = (float*)d_out;
    float* ws  = (float*)d_ws;

    // workspace layout (float-element offsets)
    unsigned short* h1b = (unsigned short*)ws;                 // N*64 bf16
    float* as1 = ws + 3200000;                                 // N*8
    float* ad1 = ws + 4000000;                                 // N*8
    unsigned short* h2b = (unsigned short*)(ws + 4800000);     // N*40 bf16
    float* as2 = ws + 6800000;                                 // N
    float* ad2 = ws + 6900000;                                 // N
    unsigned short* W1t = (unsigned short*)(ws + 7000000);     // 80*512 bf16
    int* row_ptr = (int*)(ws + 7100000);                       // N+1
    int* deg     = (int*)(ws + 7210000);                       // N
    int* cnt     = (int*)(ws + 7310000);                       // N
    int* csr_src = (int*)(ws + 7410000);                       // ETOT

    hipMemsetAsync(deg, 0, (size_t)N_NODES * sizeof(int), stream);
    hipMemsetAsync(cnt, 0, (size_t)N_NODES * sizeof(int), stream);

    k_prep<<<(NB * FIN + 255) / 256, 256, 0, stream>>>(W1, at_s1, at_d1, W1t);
    k_deg<<<(ETOT + 255) / 256, 256, 0, stream>>>(ei, deg);
    k_scan<<<1, 1024, 0, stream>>>(deg, row_ptr);
    k_scatter<<<(ETOT + 255) / 256, 256, 0, stream>>>(ei, row_ptr, cnt, csr_src);
    k_gemm1<<<(N_NODES + 127) / 128, 256, 0, stream>>>(x, W1t, h1b, as1, ad1);
    k_agg1f<<<(N_NODES + 3) / 4, 256, 0, stream>>>(h1b, as1, ad1, row_ptr, csr_src,
                                                   b1, W2, at_s2, at_d2, h2b, as2, ad2);
    k_agg2f<<<(N_NODES + 3) / 4, 256, 0, stream>>>(h2b, as2, ad2, row_ptr, csr_src, b2, out);
}

// Round 5
// 722.052 us; speedup vs baseline: 6.5292x; 1.2324x over previous
//
#include <hip/hip_runtime.h>
#include <cstdint>

#define N_NODES 100000
#define N_EDGES 1600000
#define ETOT    1700000   // edges + self loops
#define FIN     512
#define HD1     64        // 8 heads * 8 dims
#define NB      80        // 64 h1 cols + 8 as1 + 8 ad1
#define C2      40
#define NEG_SLOPE 0.2f
#define SCAN_NB ((N_NODES + 1023) / 1024)   // 98

typedef __attribute__((ext_vector_type(8))) short bf16x8;
typedef __attribute__((ext_vector_type(4))) float f32x4;

__device__ __forceinline__ float lrelu(float v) { return v > 0.f ? v : NEG_SLOPE * v; }

__device__ __forceinline__ unsigned short f2bf(float f) {
    uint32_t u = __float_as_uint(f);
    u += 0x7FFF + ((u >> 16) & 1);   // round-to-nearest-even
    return (unsigned short)(u >> 16);
}
__device__ __forceinline__ float bf2f(unsigned short u) {
    return __uint_as_float(((uint32_t)u) << 16);
}

// ---------------- prep: W1t[80][512] bf16 = [W1^T ; (W1*att_src1)^T ; (W1*att_dst1)^T] ----
__global__ void k_prep(const float* __restrict__ W1, const float* __restrict__ a_s,
                       const float* __restrict__ a_d, unsigned short* __restrict__ W1t) {
    int t = blockIdx.x * 256 + threadIdx.x;
    if (t >= NB * FIN) return;
    int n = t >> 9, k = t & 511;
    float v;
    if (n < 64) {
        v = W1[k * HD1 + n];
    } else if (n < 72) {
        int h = n - 64; v = 0.f;
#pragma unroll
        for (int d = 0; d < 8; d++) v += W1[k * HD1 + h * 8 + d] * a_s[h * 8 + d];
    } else {
        int h = n - 72; v = 0.f;
#pragma unroll
        for (int d = 0; d < 8; d++) v += W1[k * HD1 + h * 8 + d] * a_d[h * 8 + d];
    }
    W1t[n * FIN + k] = f2bf(v);
}

// ---------------- GEMM1 (MFMA bf16): [h1b | as1 | ad1] = x @ W1t^T ----------------
__global__ __launch_bounds__(256) void k_gemm1(const float* __restrict__ x,
                                               const unsigned short* __restrict__ W1t,
                                               unsigned short* __restrict__ h1b,
                                               float* __restrict__ as1,
                                               float* __restrict__ ad1) {
    __shared__ unsigned short As[128 * 72];   // chunk of x in bf16, row stride 72 (pad 8)
    const int t    = threadIdx.x;
    const int lane = t & 63, wv = t >> 6;
    const int quad = lane >> 4, l16 = lane & 15;
    const int row0 = blockIdx.x * 128;

    f32x4 acc[2][5];
#pragma unroll
    for (int mi = 0; mi < 2; mi++)
#pragma unroll
        for (int ni = 0; ni < 5; ni++) acc[mi][ni] = (f32x4){0.f, 0.f, 0.f, 0.f};

    float4 rx[8];
#pragma unroll
    for (int i = 0; i < 8; i++) {
        int ff = t + i * 256;
        int r = ff >> 4, c4 = ff & 15;
        int row = row0 + r;
        rx[i] = (row < N_NODES) ? *(const float4*)&x[(size_t)row * FIN + c4 * 4]
                                : make_float4(0.f, 0.f, 0.f, 0.f);
    }

    for (int c = 0; c < 8; c++) {
#pragma unroll
        for (int i = 0; i < 8; i++) {
            int ff = t + i * 256;
            int r = ff >> 4, c4 = ff & 15;
            ushort4 s4;
            s4.x = f2bf(rx[i].x); s4.y = f2bf(rx[i].y);
            s4.z = f2bf(rx[i].z); s4.w = f2bf(rx[i].w);
            *(ushort4*)&As[r * 72 + c4 * 4] = s4;
        }
        __syncthreads();
        if (c < 7) {
            int kb = (c + 1) * 64;
#pragma unroll
            for (int i = 0; i < 8; i++) {
                int ff = t + i * 256;
                int r = ff >> 4, c4 = ff & 15;
                int row = row0 + r;
                rx[i] = (row < N_NODES) ? *(const float4*)&x[(size_t)row * FIN + kb + c4 * 4]
                                        : make_float4(0.f, 0.f, 0.f, 0.f);
            }
        }
        int kb = c * 64;
#pragma unroll
        for (int ks = 0; ks < 2; ks++) {
            bf16x8 af[2], bfv[5];
#pragma unroll
            for (int mi = 0; mi < 2; mi++) {
                int lr = wv * 32 + mi * 16 + l16;
                af[mi] = *(const bf16x8*)&As[lr * 72 + ks * 32 + quad * 8];
            }
#pragma unroll
            for (int ni = 0; ni < 5; ni++) {
                int n = ni * 16 + l16;
                bfv[ni] = *(const bf16x8*)&W1t[n * FIN + kb + ks * 32 + quad * 8];
            }
#pragma unroll
            for (int mi = 0; mi < 2; mi++)
#pragma unroll
                for (int ni = 0; ni < 5; ni++)
                    acc[mi][ni] = __builtin_amdgcn_mfma_f32_16x16x32_bf16(
                        af[mi], bfv[ni], acc[mi][ni], 0, 0, 0);
        }
        __syncthreads();
    }
#pragma unroll
    for (int mi = 0; mi < 2; mi++)
#pragma unroll
        for (int ni = 0; ni < 5; ni++)
#pragma unroll
            for (int r = 0; r < 4; r++) {
                int row = row0 + wv * 32 + mi * 16 + quad * 4 + r;
                if (row >= N_NODES) continue;
                int col = ni * 16 + l16;
                float v = acc[mi][ni][r];
                if (col < 64)       h1b[(size_t)row * 64 + col] = f2bf(v);
                else if (col < 72)  as1[row * 8 + (col - 64)] = v;
                else                ad1[row * 8 + (col - 72)] = v;
            }
}

// ---------------- CSR build ----------------
__global__ void k_deg(const int* __restrict__ ei, int* __restrict__ deg) {
    int e = blockIdx.x * 256 + threadIdx.x;
    if (e >= ETOT) return;
    int dst = (e < N_EDGES) ? ei[N_EDGES + e] : e - N_EDGES;
    atomicAdd(&deg[dst], 1);
}

// phase A: per-block sums (coalesced)
__global__ __launch_bounds__(1024) void k_bsum(const int* __restrict__ deg,
                                               int* __restrict__ bsum) {
    __shared__ int wsm[16];
    int t = threadIdx.x;
    int i = blockIdx.x * 1024 + t;
    int v = (i < N_NODES) ? deg[i] : 0;
#pragma unroll
    for (int o = 32; o >= 1; o >>= 1) v += __shfl_xor(v, o, 64);
    if ((t & 63) == 0) wsm[t >> 6] = v;
    __syncthreads();
    if (t < 16) {
        int s = wsm[t];
#pragma unroll
        for (int o = 8; o >= 1; o >>= 1) s += __shfl_xor(s, o, 16);
        if (t == 0) bsum[blockIdx.x] = s;
    }
}

// phase B: scan the 98 block sums (1 block, 128 thr)
__global__ __launch_bounds__(128) void k_bscan(const int* __restrict__ bsum,
                                               int* __restrict__ boff) {
    __shared__ int sh[128];
    int t = threadIdx.x;
    int v = (t < SCAN_NB) ? bsum[t] : 0;
    sh[t] = v;
    __syncthreads();
    for (int off = 1; off < 128; off <<= 1) {
        int u = (t >= off) ? sh[t - off] : 0;
        __syncthreads();
        sh[t] += u;
        __syncthreads();
    }
    boff[t] = sh[t] - v;   // exclusive
}

// phase C: in-block scan + offset -> row_ptr
__global__ __launch_bounds__(1024) void k_scan3(const int* __restrict__ deg,
                                                const int* __restrict__ boff,
                                                int* __restrict__ row_ptr) {
    __shared__ int sh[1024];
    int t = threadIdx.x;
    int i = blockIdx.x * 1024 + t;
    int v = (i < N_NODES) ? deg[i] : 0;
    sh[t] = v;
    __syncthreads();
    for (int off = 1; off < 1024; off <<= 1) {
        int u = (t >= off) ? sh[t - off] : 0;
        __syncthreads();
        sh[t] += u;
        __syncthreads();
    }
    int base = boff[blockIdx.x];
    if (i < N_NODES) row_ptr[i] = base + sh[t] - v;
    if (i == N_NODES - 1) row_ptr[N_NODES] = base + sh[t];
}

__global__ void k_scatter(const int* __restrict__ ei, const int* __restrict__ row_ptr,
                          int* __restrict__ cnt, int* __restrict__ csr_src) {
    int e = blockIdx.x * 256 + threadIdx.x;
    if (e >= ETOT) return;
    int src, dst;
    if (e < N_EDGES) { src = ei[e]; dst = ei[N_EDGES + e]; }
    else             { src = dst = e - N_EDGES; }
    int pos = row_ptr[dst] + atomicAdd(&cnt[dst], 1);
    csr_src[pos] = src;
}

// ---------------- layer 1: gather-aggregate + ELU + GEMM2 + att2 logits ----------------
__global__ __launch_bounds__(256) void k_agg1f(
    const unsigned short* __restrict__ h1b,
    const float* __restrict__ as1, const float* __restrict__ ad1,
    const int* __restrict__ row_ptr, const int* __restrict__ csr_src,
    const float* __restrict__ b1, const float* __restrict__ W2,
    const float* __restrict__ att_s2, const float* __restrict__ att_d2,
    unsigned short* __restrict__ h2b, float* __restrict__ as2, float* __restrict__ ad2) {
    __shared__ float w2s[64 * C2];
    int t = threadIdx.x;
    for (int i = t; i < 64 * C2; i += 256) w2s[i] = W2[i];
    __syncthreads();
    int wv = t >> 6, lane = t & 63;
    int dst = blockIdx.x * 4 + wv;
    if (dst >= N_NODES) return;
    int h  = lane >> 3;
    int hh = lane & 7;
    int s0 = row_ptr[dst], s1e = row_ptr[dst + 1];
    float adh = ad1[dst * 8 + hh];
    float acc = 0.f, den = 0.f;
    for (int base = s0; base < s1e; base += 8) {
        int eidx = base + (lane >> 3);
        bool vld = eidx < s1e;
        int sl = vld ? csr_src[eidx] : 0;
        float wl = vld ? __expf(lrelu(as1[sl * 8 + hh] + adh)) : 0.f;
#pragma unroll
        for (int j = 0; j < 8; j++) {
            int s   = __shfl(sl, j * 8);
            float w = __shfl(wl, j * 8 + h);
            den += w;
            acc += w * bf2f(h1b[(size_t)s * 64 + lane]);
        }
    }
    float hv = acc / (den + 1e-16f) + b1[lane];
    hv = hv > 0.f ? hv : expm1f(hv);
    int c = (lane < C2) ? lane : 0;
    float a2 = 0.f;
#pragma unroll
    for (int k = 0; k < 64; k++) a2 += __shfl(hv, k, 64) * w2s[k * C2 + c];
    float sa = (lane < C2) ? a2 * att_s2[c] : 0.f;
    float da = (lane < C2) ? a2 * att_d2[c] : 0.f;
#pragma unroll
    for (int o = 32; o >= 1; o >>= 1) {
        sa += __shfl_xor(sa, o, 64);
        da += __shfl_xor(da, o, 64);
    }
    if (lane < C2) h2b[(size_t)dst * C2 + lane] = f2bf(a2);
    if (lane == 0) { as2[dst] = sa; ad2[dst] = da; }
}

// ---------------- layer 2: gather-aggregate + bias + log_softmax ----------------
__global__ __launch_bounds__(256) void k_agg2f(
    const unsigned short* __restrict__ h2b,
    const float* __restrict__ as2, const float* __restrict__ ad2,
    const int* __restrict__ row_ptr, const int* __restrict__ csr_src,
    const float* __restrict__ b2, float* __restrict__ out) {
    int t = threadIdx.x, wv = t >> 6, lane = t & 63;
    int dst = blockIdx.x * 4 + wv;
    if (dst >= N_NODES) return;
    int s0 = row_ptr[dst], s1e = row_ptr[dst + 1];
    float ad = ad2[dst];
    bool act = lane < C2;
    int cl = act ? lane : 0;
    float acc = 0.f, den = 0.f;
    for (int base = s0; base < s1e; base += 64) {
        int idx = base + lane;
        bool vld = idx < s1e;
        int sl = vld ? csr_src[idx] : 0;
        float wl = vld ? __expf(lrelu(as2[sl] + ad)) : 0.f;
        float d = wl;
#pragma unroll
        for (int o = 32; o >= 1; o >>= 1) d += __shfl_xor(d, o, 64);
        den += d;
        int cnt  = min(64, s1e - base);
        int cnt4 = (cnt + 3) & ~3;
        for (int j = 0; j < cnt4; j += 4) {
#pragma unroll
            for (int jj = 0; jj < 4; jj++) {
                int s   = __shfl(sl, j + jj);
                float w = __shfl(wl, j + jj);
                float hvv = bf2f(h2b[(size_t)s * C2 + cl]);
                if (act) acc += w * hvv;
            }
        }
    }
    float v = act ? acc / (den + 1e-16f) + b2[cl] : -1e30f;
    float m = v;
#pragma unroll
    for (int o = 32; o >= 1; o >>= 1) m = fmaxf(m, __shfl_xor(m, o, 64));
    float ex = act ? __expf(v - m) : 0.f;
    float ssum = ex;
#pragma unroll
    for (int o = 32; o >= 1; o >>= 1) ssum += __shfl_xor(ssum, o, 64);
    if (act) out[(size_t)dst * C2 + lane] = v - m - logf(ssum);
}

extern "C" void kernel_launch(void* const* d_in, const int* in_sizes, int n_in,
                              void* d_out, int out_size, void* d_ws, size_t ws_size,
                              hipStream_t stream) {
    const float* x     = (const float*)d_in[0];
    const int*   ei    = (const int*)d_in[1];
    const float* W1    = (const float*)d_in[2];
    const float* at_s1 = (const float*)d_in[3];
    const float* at_d1 = (const float*)d_in[4];
    const float* b1    = (const float*)d_in[5];
    const float* W2    = (const float*)d_in[6];
    const float* at_s2 = (const float*)d_in[7];
    const float* at_d2 = (const float*)d_in[8];
    const float* b2    = (const float*)d_in[9];
    float* out = (float*)d_out;
    float* ws  = (float*)d_ws;

    // workspace layout (float-element offsets) — NON-OVERLAPPING:
    // [0, 3.2M) h1b | [3.2M,4M) as1 | [4M,4.8M) ad1 | [4.8M,6.8M) h2b
    // [6.8M,6.9M) as2 | [6.9M,7.0M) ad2 | [7.0M,7.1M) W1t
    // [7.1M,7.21M) row_ptr | [7.21M,7.31M) deg | [7.31M,7.41M) cnt
    // [7.41M,9.11M) csr_src | [9.12M,..) bsum | [9.13M,..) boff
    unsigned short* h1b = (unsigned short*)ws;                 // N*64 bf16
    float* as1 = ws + 3200000;                                 // N*8
    float* ad1 = ws + 4000000;                                 // N*8
    unsigned short* h2b = (unsigned short*)(ws + 4800000);     // N*40 bf16
    float* as2 = ws + 6800000;                                 // N
    float* ad2 = ws + 6900000;                                 // N
    unsigned short* W1t = (unsigned short*)(ws + 7000000);     // 80*512 bf16
    int* row_ptr = (int*)(ws + 7100000);                       // N+1
    int* deg     = (int*)(ws + 7210000);                       // N
    int* cnt     = (int*)(ws + 7310000);                       // N
    int* csr_src = (int*)(ws + 7410000);                       // ETOT -> ends 9,110,000
    int* bsum    = (int*)(ws + 9120000);                       // 98
    int* boff    = (int*)(ws + 9130000);                       // 128

    hipMemsetAsync(deg, 0, (size_t)N_NODES * sizeof(int), stream);
    hipMemsetAsync(cnt, 0, (size_t)N_NODES * sizeof(int), stream);

    k_prep<<<(NB * FIN + 255) / 256, 256, 0, stream>>>(W1, at_s1, at_d1, W1t);
    k_deg<<<(ETOT + 255) / 256, 256, 0, stream>>>(ei, deg);
    k_bsum<<<SCAN_NB, 1024, 0, stream>>>(deg, bsum);
    k_bscan<<<1, 128, 0, stream>>>(bsum, boff);
    k_scan3<<<SCAN_NB, 1024, 0, stream>>>(deg, boff, row_ptr);
    k_scatter<<<(ETOT + 255) / 256, 256, 0, stream>>>(ei, row_ptr, cnt, csr_src);
    k_gemm1<<<(N_NODES + 127) / 128, 256, 0, stream>>>(x, W1t, h1b, as1, ad1);
    k_agg1f<<<(N_NODES + 3) / 4, 256, 0, stream>>>(h1b, as1, ad1, row_ptr, csr_src,
                                                   b1, W2, at_s2, at_d2, h2b, as2, ad2);
    k_agg2f<<<(N_NODES + 3) / 4, 256, 0, stream>>>(h2b, as2, ad2, row_ptr, csr_src, b2, out);
}

// Round 6
// 620.135 us; speedup vs baseline: 7.6022x; 1.1643x over previous
//
#include <hip/hip_runtime.h>
#include <cstdint>

#define N_NODES 100000
#define N_EDGES 1600000
#define ETOT    1700000   // edges + self loops
#define FIN     512
#define HD1     64        // 8 heads * 8 dims
#define NB      80        // 64 h1 cols + 8 as1 + 8 ad1
#define C2      40
#define NEG_SLOPE 0.2f
#define SCAN_NB ((N_NODES + 1023) / 1024)   // 98

typedef __attribute__((ext_vector_type(8))) short bf16x8;
typedef __attribute__((ext_vector_type(4))) float f32x4;

__device__ __forceinline__ float lrelu(float v) { return v > 0.f ? v : NEG_SLOPE * v; }

__device__ __forceinline__ unsigned short f2bf(float f) {
    uint32_t u = __float_as_uint(f);
    u += 0x7FFF + ((u >> 16) & 1);   // round-to-nearest-even
    return (unsigned short)(u >> 16);
}
__device__ __forceinline__ float bf2f(unsigned short u) {
    return __uint_as_float(((uint32_t)u) << 16);
}

// ---------------- prep (merged):
// blocks [0,160):  W1t[80][512] bf16 = [W1^T ; (W1*att_src1)^T ; (W1*att_dst1)^T]
// blocks [160,172): W2t[48][64] bf16 = [W2col ; W2*att_s2 ; W2*att_d2 ; 0pad]
__global__ void k_prep(const float* __restrict__ W1, const float* __restrict__ a_s,
                       const float* __restrict__ a_d,
                       const float* __restrict__ W2, const float* __restrict__ att_s2,
                       const float* __restrict__ att_d2,
                       unsigned short* __restrict__ W1t, unsigned short* __restrict__ W2t) {
    if (blockIdx.x < 160) {
        int t = blockIdx.x * 256 + threadIdx.x;   // < 40960 = 80*512
        int n = t >> 9, k = t & 511;
        float v;
        if (n < 64) {
            v = W1[k * HD1 + n];
        } else if (n < 72) {
            int h = n - 64; v = 0.f;
#pragma unroll
            for (int d = 0; d < 8; d++) v += W1[k * HD1 + h * 8 + d] * a_s[h * 8 + d];
        } else {
            int h = n - 72; v = 0.f;
#pragma unroll
            for (int d = 0; d < 8; d++) v += W1[k * HD1 + h * 8 + d] * a_d[h * 8 + d];
        }
        W1t[n * FIN + k] = f2bf(v);
    } else {
        int t = (blockIdx.x - 160) * 256 + threadIdx.x;
        if (t >= 48 * 64) return;
        int n = t >> 6, k = t & 63;
        float v = 0.f;
        if (n < C2) {
            v = W2[k * C2 + n];
        } else if (n == C2) {
            for (int c = 0; c < C2; c++) v += W2[k * C2 + c] * att_s2[c];
        } else if (n == C2 + 1) {
            for (int c = 0; c < C2; c++) v += W2[k * C2 + c] * att_d2[c];
        }
        W2t[n * 64 + k] = f2bf(v);
    }
}

// ---------------- GEMM1 (MFMA bf16): [h1b | as1 | ad1] = x @ W1t^T ----------------
__global__ __launch_bounds__(256) void k_gemm1(const float* __restrict__ x,
                                               const unsigned short* __restrict__ W1t,
                                               unsigned short* __restrict__ h1b,
                                               float* __restrict__ as1,
                                               float* __restrict__ ad1) {
    __shared__ unsigned short As[128 * 72];   // chunk of x in bf16, row stride 72 (pad 8)
    const int t    = threadIdx.x;
    const int lane = t & 63, wv = t >> 6;
    const int quad = lane >> 4, l16 = lane & 15;
    const int row0 = blockIdx.x * 128;

    f32x4 acc[2][5];
#pragma unroll
    for (int mi = 0; mi < 2; mi++)
#pragma unroll
        for (int ni = 0; ni < 5; ni++) acc[mi][ni] = (f32x4){0.f, 0.f, 0.f, 0.f};

    float4 rx[8];
#pragma unroll
    for (int i = 0; i < 8; i++) {
        int ff = t + i * 256;
        int r = ff >> 4, c4 = ff & 15;
        int row = row0 + r;
        rx[i] = (row < N_NODES) ? *(const float4*)&x[(size_t)row * FIN + c4 * 4]
                                : make_float4(0.f, 0.f, 0.f, 0.f);
    }

    for (int c = 0; c < 8; c++) {
#pragma unroll
        for (int i = 0; i < 8; i++) {
            int ff = t + i * 256;
            int r = ff >> 4, c4 = ff & 15;
            ushort4 s4;
            s4.x = f2bf(rx[i].x); s4.y = f2bf(rx[i].y);
            s4.z = f2bf(rx[i].z); s4.w = f2bf(rx[i].w);
            *(ushort4*)&As[r * 72 + c4 * 4] = s4;
        }
        __syncthreads();
        if (c < 7) {
            int kb = (c + 1) * 64;
#pragma unroll
            for (int i = 0; i < 8; i++) {
                int ff = t + i * 256;
                int r = ff >> 4, c4 = ff & 15;
                int row = row0 + r;
                rx[i] = (row < N_NODES) ? *(const float4*)&x[(size_t)row * FIN + kb + c4 * 4]
                                        : make_float4(0.f, 0.f, 0.f, 0.f);
            }
        }
        int kb = c * 64;
#pragma unroll
        for (int ks = 0; ks < 2; ks++) {
            bf16x8 af[2], bfv[5];
#pragma unroll
            for (int mi = 0; mi < 2; mi++) {
                int lr = wv * 32 + mi * 16 + l16;
                af[mi] = *(const bf16x8*)&As[lr * 72 + ks * 32 + quad * 8];
            }
#pragma unroll
            for (int ni = 0; ni < 5; ni++) {
                int n = ni * 16 + l16;
                bfv[ni] = *(const bf16x8*)&W1t[n * FIN + kb + ks * 32 + quad * 8];
            }
#pragma unroll
            for (int mi = 0; mi < 2; mi++)
#pragma unroll
                for (int ni = 0; ni < 5; ni++)
                    acc[mi][ni] = __builtin_amdgcn_mfma_f32_16x16x32_bf16(
                        af[mi], bfv[ni], acc[mi][ni], 0, 0, 0);
        }
        __syncthreads();
    }
#pragma unroll
    for (int mi = 0; mi < 2; mi++)
#pragma unroll
        for (int ni = 0; ni < 5; ni++)
#pragma unroll
            for (int r = 0; r < 4; r++) {
                int row = row0 + wv * 32 + mi * 16 + quad * 4 + r;
                if (row >= N_NODES) continue;
                int col = ni * 16 + l16;
                float v = acc[mi][ni][r];
                if (col < 64)       h1b[(size_t)row * 64 + col] = f2bf(v);
                else if (col < 72)  as1[row * 8 + (col - 64)] = v;
                else                ad1[row * 8 + (col - 72)] = v;
            }
}

// ---------------- CSR build ----------------
__global__ void k_deg(const int* __restrict__ ei, int* __restrict__ deg) {
    int e = blockIdx.x * 256 + threadIdx.x;
    if (e >= ETOT) return;
    int dst = (e < N_EDGES) ? ei[N_EDGES + e] : e - N_EDGES;
    atomicAdd(&deg[dst], 1);
}

__global__ __launch_bounds__(1024) void k_bsum(const int* __restrict__ deg,
                                               int* __restrict__ bsum) {
    __shared__ int wsm[16];
    int t = threadIdx.x;
    int i = blockIdx.x * 1024 + t;
    int v = (i < N_NODES) ? deg[i] : 0;
#pragma unroll
    for (int o = 32; o >= 1; o >>= 1) v += __shfl_xor(v, o, 64);
    if ((t & 63) == 0) wsm[t >> 6] = v;
    __syncthreads();
    if (t < 16) {
        int s = wsm[t];
#pragma unroll
        for (int o = 8; o >= 1; o >>= 1) s += __shfl_xor(s, o, 16);
        if (t == 0) bsum[blockIdx.x] = s;
    }
}

__global__ __launch_bounds__(128) void k_bscan(const int* __restrict__ bsum,
                                               int* __restrict__ boff) {
    __shared__ int sh[128];
    int t = threadIdx.x;
    int v = (t < SCAN_NB) ? bsum[t] : 0;
    sh[t] = v;
    __syncthreads();
    for (int off = 1; off < 128; off <<= 1) {
        int u = (t >= off) ? sh[t - off] : 0;
        __syncthreads();
        sh[t] += u;
        __syncthreads();
    }
    boff[t] = sh[t] - v;   // exclusive
}

__global__ __launch_bounds__(1024) void k_scan3(const int* __restrict__ deg,
                                                const int* __restrict__ boff,
                                                int* __restrict__ row_ptr) {
    __shared__ int sh[1024];
    int t = threadIdx.x;
    int i = blockIdx.x * 1024 + t;
    int v = (i < N_NODES) ? deg[i] : 0;
    sh[t] = v;
    __syncthreads();
    for (int off = 1; off < 1024; off <<= 1) {
        int u = (t >= off) ? sh[t - off] : 0;
        __syncthreads();
        sh[t] += u;
        __syncthreads();
    }
    int base = boff[blockIdx.x];
    if (i < N_NODES) row_ptr[i] = base + sh[t] - v;
    if (i == N_NODES - 1) row_ptr[N_NODES] = base + sh[t];
}

__global__ void k_scatter(const int* __restrict__ ei, const int* __restrict__ row_ptr,
                          int* __restrict__ cnt, int* __restrict__ csr_src) {
    int e = blockIdx.x * 256 + threadIdx.x;
    if (e >= ETOT) return;
    int src, dst;
    if (e < N_EDGES) { src = ei[e]; dst = ei[N_EDGES + e]; }
    else             { src = dst = e - N_EDGES; }
    int pos = row_ptr[dst] + atomicAdd(&cnt[dst], 1);
    csr_src[pos] = src;
}

// ---------------- layer 1: gather-aggregate + bias + ELU -> hb (bf16) ----------------
// one wave per dst; lane = channel (h = lane>>3)
__global__ __launch_bounds__(256) void k_agg1(
    const unsigned short* __restrict__ h1b,
    const float* __restrict__ as1, const float* __restrict__ ad1,
    const int* __restrict__ row_ptr, const int* __restrict__ csr_src,
    const float* __restrict__ b1, unsigned short* __restrict__ hb) {
    int t = threadIdx.x, wv = t >> 6, lane = t & 63;
    int dst = blockIdx.x * 4 + wv;
    if (dst >= N_NODES) return;
    int h = lane >> 3;
    int s0 = row_ptr[dst], s1e = row_ptr[dst + 1];
    float adh = ad1[dst * 8 + h];
    float acc = 0.f, den = 0.f;
    for (int base = s0; base < s1e; base += 64) {
        int idx = base + lane;
        int sl = (idx < s1e) ? csr_src[idx] : 0;
        int cnt = min(64, s1e - base);
        int j = 0;
        for (; j + 4 <= cnt; j += 4) {
#pragma unroll
            for (int jj = 0; jj < 4; jj++) {
                int s = __shfl(sl, j + jj);
                float w = __expf(lrelu(as1[s * 8 + h] + adh));
                den += w;
                acc += w * bf2f(h1b[(size_t)s * 64 + lane]);
            }
        }
        for (; j < cnt; j++) {
            int s = __shfl(sl, j);
            float w = __expf(lrelu(as1[s * 8 + h] + adh));
            den += w;
            acc += w * bf2f(h1b[(size_t)s * 64 + lane]);
        }
    }
    float hv = acc / (den + 1e-16f) + b1[lane];
    hv = hv > 0.f ? hv : expm1f(hv);
    hb[(size_t)dst * 64 + lane] = f2bf(hv);
}

// ---------------- GEMM2 (MFMA bf16): [h2b | as2 | ad2] = hb @ W2t^T ----------------
// 256 thr = 4 waves; tile M=128 (wave: 32 rows), N=48 (3 n-tiles); K=64; no LDS
__global__ __launch_bounds__(256) void k_gemm2(const unsigned short* __restrict__ hb,
                                               const unsigned short* __restrict__ W2t,
                                               unsigned short* __restrict__ h2b,
                                               float* __restrict__ as2,
                                               float* __restrict__ ad2) {
    const int t = threadIdx.x;
    const int lane = t & 63, wv = t >> 6;
    const int quad = lane >> 4, l16 = lane & 15;
    const int row0 = blockIdx.x * 128;

    f32x4 acc[2][3];
#pragma unroll
    for (int mi = 0; mi < 2; mi++)
#pragma unroll
        for (int ni = 0; ni < 3; ni++) acc[mi][ni] = (f32x4){0.f, 0.f, 0.f, 0.f};

    bf16x8 bfrag[2][3];
#pragma unroll
    for (int ks = 0; ks < 2; ks++)
#pragma unroll
        for (int ni = 0; ni < 3; ni++)
            bfrag[ks][ni] = *(const bf16x8*)&W2t[(ni * 16 + l16) * 64 + ks * 32 + quad * 8];

#pragma unroll
    for (int mi = 0; mi < 2; mi++) {
        int row = row0 + wv * 32 + mi * 16 + l16;
        int rowc = row < N_NODES ? row : N_NODES - 1;   // clamp (epilogue masks)
#pragma unroll
        for (int ks = 0; ks < 2; ks++) {
            bf16x8 af = *(const bf16x8*)&hb[(size_t)rowc * 64 + ks * 32 + quad * 8];
#pragma unroll
            for (int ni = 0; ni < 3; ni++)
                acc[mi][ni] = __builtin_amdgcn_mfma_f32_16x16x32_bf16(
                    af, bfrag[ks][ni], acc[mi][ni], 0, 0, 0);
        }
    }
#pragma unroll
    for (int mi = 0; mi < 2; mi++)
#pragma unroll
        for (int ni = 0; ni < 3; ni++)
#pragma unroll
            for (int r = 0; r < 4; r++) {
                int row = row0 + wv * 32 + mi * 16 + quad * 4 + r;
                if (row >= N_NODES) continue;
                int col = ni * 16 + l16;
                float v = acc[mi][ni][r];
                if (col < C2)            h2b[(size_t)row * C2 + col] = f2bf(v);
                else if (col == C2)      as2[row] = v;
                else if (col == C2 + 1)  ad2[row] = v;
            }
}

// ---------------- layer 2: gather-aggregate + bias + log_softmax ----------------
__global__ __launch_bounds__(256) void k_agg2(
    const unsigned short* __restrict__ h2b,
    const float* __restrict__ as2, const float* __restrict__ ad2,
    const int* __restrict__ row_ptr, const int* __restrict__ csr_src,
    const float* __restrict__ b2, float* __restrict__ out) {
    int t = threadIdx.x, wv = t >> 6, lane = t & 63;
    int dst = blockIdx.x * 4 + wv;
    if (dst >= N_NODES) return;
    int s0 = row_ptr[dst], s1e = row_ptr[dst + 1];
    float ad = ad2[dst];
    bool act = lane < C2;
    int cl = act ? lane : 0;
    float acc = 0.f, den = 0.f;
    for (int base = s0; base < s1e; base += 64) {
        int idx = base + lane;
        bool vld = idx < s1e;
        int sl = vld ? csr_src[idx] : 0;
        float wl = vld ? __expf(lrelu(as2[sl] + ad)) : 0.f;
        float d = wl;
#pragma unroll
        for (int o = 32; o >= 1; o >>= 1) d += __shfl_xor(d, o, 64);
        den += d;
        int cnt  = min(64, s1e - base);
        int cnt4 = (cnt + 3) & ~3;
        for (int j = 0; j < cnt4; j += 4) {
#pragma unroll
            for (int jj = 0; jj < 4; jj++) {
                int s   = __shfl(sl, j + jj);
                float w = __shfl(wl, j + jj);
                float hvv = bf2f(h2b[(size_t)s * C2 + cl]);
                if (act) acc += w * hvv;
            }
        }
    }
    float v = act ? acc / (den + 1e-16f) + b2[cl] : -1e30f;
    float m = v;
#pragma unroll
    for (int o = 32; o >= 1; o >>= 1) m = fmaxf(m, __shfl_xor(m, o, 64));
    float ex = act ? __expf(v - m) : 0.f;
    float ssum = ex;
#pragma unroll
    for (int o = 32; o >= 1; o >>= 1) ssum += __shfl_xor(ssum, o, 64);
    if (act) out[(size_t)dst * C2 + lane] = v - m - logf(ssum);
}

extern "C" void kernel_launch(void* const* d_in, const int* in_sizes, int n_in,
                              void* d_out, int out_size, void* d_ws, size_t ws_size,
                              hipStream_t stream) {
    const float* x     = (const float*)d_in[0];
    const int*   ei    = (const int*)d_in[1];
    const float* W1    = (const float*)d_in[2];
    const float* at_s1 = (const float*)d_in[3];
    const float* at_d1 = (const float*)d_in[4];
    const float* b1    = (const float*)d_in[5];
    const float* W2    = (const float*)d_in[6];
    const float* at_s2 = (const float*)d_in[7];
    const float* at_d2 = (const float*)d_in[8];
    const float* b2    = (const float*)d_in[9];
    float* out = (float*)d_out;
    float* ws  = (float*)d_ws;

    // workspace layout (float-element offsets) — NON-OVERLAPPING:
    unsigned short* h1b = (unsigned short*)ws;                 // [0, 3.2M)  N*64 bf16
    float* as1 = ws + 3200000;                                 // [3.2M,4.0M)
    float* ad1 = ws + 4000000;                                 // [4.0M,4.8M)
    unsigned short* hb  = (unsigned short*)(ws + 4800000);     // [4.8M,8.0M) N*64 bf16
    unsigned short* h2b = (unsigned short*)(ws + 8000000);     // [8.0M,10.0M) N*40 bf16
    float* as2 = ws + 10000000;                                // [10.0M,10.1M)
    float* ad2 = ws + 10100000;                                // [10.1M,10.2M)
    unsigned short* W1t = (unsigned short*)(ws + 10200000);    // 40960 ush
    unsigned short* W2t = (unsigned short*)(ws + 10250000);    // 3072 ush
    int* row_ptr = (int*)(ws + 10300000);                      // N+1
    int* deg     = (int*)(ws + 10410000);                      // N
    int* cnt     = (int*)(ws + 10520000);                      // N
    int* csr_src = (int*)(ws + 10630000);                      // ETOT -> ends 12.33M
    int* bsum    = (int*)(ws + 12340000);                      // 98
    int* boff    = (int*)(ws + 12350000);                      // 128

    hipMemsetAsync(deg, 0, (size_t)N_NODES * sizeof(int), stream);
    hipMemsetAsync(cnt, 0, (size_t)N_NODES * sizeof(int), stream);

    k_prep<<<172, 256, 0, stream>>>(W1, at_s1, at_d1, W2, at_s2, at_d2, W1t, W2t);
    k_deg<<<(ETOT + 255) / 256, 256, 0, stream>>>(ei, deg);
    k_bsum<<<SCAN_NB, 1024, 0, stream>>>(deg, bsum);
    k_bscan<<<1, 128, 0, stream>>>(bsum, boff);
    k_scan3<<<SCAN_NB, 1024, 0, stream>>>(deg, boff, row_ptr);
    k_scatter<<<(ETOT + 255) / 256, 256, 0, stream>>>(ei, row_ptr, cnt, csr_src);
    k_gemm1<<<(N_NODES + 127) / 128, 256, 0, stream>>>(x, W1t, h1b, as1, ad1);
    k_agg1<<<(N_NODES + 3) / 4, 256, 0, stream>>>(h1b, as1, ad1, row_ptr, csr_src, b1, hb);
    k_gemm2<<<(N_NODES + 127) / 128, 256, 0, stream>>>(hb, W2t, h2b, as2, ad2);
    k_agg2<<<(N_NODES + 3) / 4, 256, 0, stream>>>(h2b, as2, ad2, row_ptr, csr_src, b2, out);
}